// Round 1
// baseline (2312.308 us; speedup 1.0000x reference)
//
#include <hip/hip_runtime.h>
#include <hip/hip_bf16.h>

// CIN (xDeepFM-style) fused kernel, fp32 correctness-first baseline.
//
// Shapes: B=256, F0=40, K=32, layers Fi -> 200 with Fi in {40, 200}.
// Per layer:
//   x0_wk[b,f0,k] = inputs * wk ; x0_wv = inputs * wv ; xi_wq[b,fi,k] = res * wq
//   phi[b,k,f0,fi] = x0_wk[b,f0,k] * xi_wq[b,fi,k]          (outer product per (b,k))
//   alpha = softmax over f0 (40 elems)
//   X[b,k,c=(f0*Fi+fi)] = alpha * x0_wv[b,f0,k]
//   out[b,j,k] = sum_c X[b,k,c] * cw[c,j]                    (the dominant GEMM)
// Final: concat layer outputs on j, sum over k -> d_out [B,400].
//
// Block = one batch b. 640 threads = 20 j-groups x 32 k-lanes.
// fi processed in chunks of 8: X chunk [8][40][32] fp32 = 40KB LDS.

#define NB 256
#define NF0 40
#define KD 32
#define NOUT 200
#define NTHR 640

template<int FI>
__global__ __launch_bounds__(NTHR)
void cin_layer_kernel(const float* __restrict__ x0,    // [B,40,32] inputs
                      const float* __restrict__ res,   // [B,FI,32] (== x0 for layer 0)
                      const float* __restrict__ wq,    // [FI,32]
                      const float* __restrict__ wk,    // [40,32]
                      const float* __restrict__ wv,    // [40,32]
                      const float* __restrict__ cw,    // [40*FI, 200]
                      float* __restrict__ res_out,     // [B,200,32] or nullptr (last layer)
                      float* __restrict__ out,         // [B,400]
                      int out_off)
{
    constexpr int FC = 8;            // fi chunk
    constexpr int NCH = FI / FC;     // 5 or 25 chunks

    __shared__ float s_wk[NF0 * KD];         // 5 KB
    __shared__ float s_wv[NF0 * KD];         // 5 KB
    __shared__ float s_q[FI * KD];           // 5 or 25.6 KB
    __shared__ float s_X[FC * NF0 * KD];     // 40 KB  [fic][f0][k]
    __shared__ float s_dinv[FC * KD];        // 1 KB   [fic][k]

    const int tid = threadIdx.x;
    const int b   = blockIdx.x;
    const int k   = tid & 31;        // embedding slot
    const int jg  = tid >> 5;        // j-group 0..19, each owns 10 consecutive j

    // ---- Phase A: stage elementwise products into LDS ----
    for (int idx = tid; idx < NF0 * KD; idx += NTHR) {
        float v = x0[b * NF0 * KD + idx];
        s_wk[idx] = v * wk[idx];
        s_wv[idx] = v * wv[idx];
    }
    for (int idx = tid; idx < FI * KD; idx += NTHR) {
        s_q[idx] = res[b * FI * KD + idx] * wq[idx];
    }
    __syncthreads();

    float acc[10];
    #pragma unroll
    for (int jj = 0; jj < 10; ++jj) acc[jj] = 0.0f;

    for (int ch = 0; ch < NCH; ++ch) {
        const int fi0 = ch * FC;

        // exp(phi) fill: 10240 elems / 640 threads = 16 each, lane-consecutive k
        for (int idx = tid; idx < FC * NF0 * KD; idx += NTHR) {
            int kk  = idx & 31;
            int f0  = (idx >> 5) % NF0;
            int fic = idx / (NF0 * KD);
            s_X[idx] = __expf(s_wk[f0 * KD + kk] * s_q[(fi0 + fic) * KD + kk]);
        }
        __syncthreads();

        // softmax denominator over f0: 256 (fic,k) pairs
        if (tid < FC * KD) {
            int kk  = tid & 31;
            int fic = tid >> 5;
            float d = 0.0f;
            #pragma unroll
            for (int f0 = 0; f0 < NF0; ++f0) d += s_X[(fic * NF0 + f0) * KD + kk];
            s_dinv[tid] = 1.0f / d;
        }
        __syncthreads();

        // rescale: X = exp/D * x0_wv
        for (int idx = tid; idx < FC * NF0 * KD; idx += NTHR) {
            int kk  = idx & 31;
            int f0  = (idx >> 5) % NF0;
            int fic = idx / (NF0 * KD);
            s_X[idx] = s_X[idx] * s_dinv[fic * KD + kk] * s_wv[f0 * KD + kk];
        }
        __syncthreads();

        // GEMM accumulate: acc[jj] += X[k, c] * cw[c, jg*10+jj]
        // cw row for c=(f0*FI + fi0+fic); addresses uniform per half-wave (broadcast)
        const float* cwbase = cw + (size_t)fi0 * NOUT + jg * 10;
        const float* cwrow  = cwbase;
        for (int f0 = 0; f0 < NF0; ++f0) {
            #pragma unroll
            for (int fic = 0; fic < FC; ++fic) {
                float xv = s_X[(fic * NF0 + f0) * KD + k];
                const float* cp = cwrow + fic * NOUT;
                #pragma unroll
                for (int jj = 0; jj < 10; ++jj)
                    acc[jj] = fmaf(xv, cp[jj], acc[jj]);
            }
            cwrow += (size_t)FI * NOUT;
        }
        __syncthreads();   // s_X reused next chunk
    }

    // ---- Epilogue ----
    // Stage out[j][k] into LDS (reuse s_X) for the next layer's res
    if (res_out != nullptr) {
        float* s_out = s_X;   // 200*32 = 25.6KB <= 40KB
        #pragma unroll
        for (int jj = 0; jj < 10; ++jj)
            s_out[(jg * 10 + jj) * KD + k] = acc[jj];
        __syncthreads();
        for (int idx = tid; idx < NOUT * KD; idx += NTHR)
            res_out[b * NOUT * KD + idx] = s_out[idx];
    }

    // k-sum: butterfly within each 32-lane half (each half holds all 32 k for one jg)
    #pragma unroll
    for (int jj = 0; jj < 10; ++jj) {
        float v = acc[jj];
        v += __shfl_xor(v, 1);
        v += __shfl_xor(v, 2);
        v += __shfl_xor(v, 4);
        v += __shfl_xor(v, 8);
        v += __shfl_xor(v, 16);
        acc[jj] = v;
    }
    if (k == 0) {
        #pragma unroll
        for (int jj = 0; jj < 10; ++jj)
            out[b * 400 + out_off + jg * 10 + jj] = acc[jj];
    }
}

extern "C" void kernel_launch(void* const* d_in, const int* in_sizes, int n_in,
                              void* d_out, int out_size, void* d_ws, size_t ws_size,
                              hipStream_t stream) {
    const float* x0  = (const float*)d_in[0];
    const float* wq0 = (const float*)d_in[1];
    const float* wk0 = (const float*)d_in[2];
    const float* wv0 = (const float*)d_in[3];
    const float* cw0 = (const float*)d_in[4];
    const float* wq1 = (const float*)d_in[5];
    const float* wk1 = (const float*)d_in[6];
    const float* wv1 = (const float*)d_in[7];
    const float* cw1 = (const float*)d_in[8];
    float* out = (float*)d_out;
    float* res = (float*)d_ws;   // [256,200,32] fp32 = 6.55 MB, fully rewritten each launch

    // Layer 0: res input == inputs (Fi=40)
    cin_layer_kernel<40><<<NB, NTHR, 0, stream>>>(x0, x0, wq0, wk0, wv0, cw0,
                                                  res, out, 0);
    // Layer 1: Fi=200, reads res written by layer 0
    cin_layer_kernel<200><<<NB, NTHR, 0, stream>>>(x0, res, wq1, wk1, wv1, cw1,
                                                   nullptr, out, 200);
}

// Round 2
// 387.077 us; speedup vs baseline: 5.9738x; 5.9738x over previous
//
#include <hip/hip_runtime.h>
#include <hip/hip_bf16.h>

// CIN (xDeepFM-style), round 2: bf16-MFMA GEMM phase.
//
// Per layer:  out[b,j,k] = sum_c X[b,k,c] * cw[c,j],  c = f0*FI + fi
//   X = softmax_f0(xk[f0,k]*q[fi,k]) * xv[f0,k]
// GEMM as MFMA 16x16x32 bf16: A = X^T chunk in LDS (bf16), B = cwT (bf16,
// pre-transposed [j][c] with j padded to 208).
//
// Verified fragment layouts (learn_hip m89/m91):
//   A[l&15][8*(l>>4)+i],  B[8*(l>>4)+i][l&15],  D[(l>>4)*4+r][l&15]

#define NB   256
#define NF0  40
#define KD   32
#define NOUT 200
#define NTP  208      // padded N (13 tiles of 16)
#define FC   8        // fi chunk
#define NTHR 512

typedef short bf16x8 __attribute__((ext_vector_type(8)));
typedef float f32x4  __attribute__((ext_vector_type(4)));

static __device__ __forceinline__ unsigned short f2bf(float f) {
    __hip_bfloat16 h = __float2bfloat16(f);
    return *reinterpret_cast<unsigned short*>(&h);
}

// ---------- pre-pass: cw [C,200] fp32 -> cwT [208,C] bf16 (zero-padded) ----------
__global__ __launch_bounds__(256)
void cw_to_bf16T(const float* __restrict__ cw, unsigned short* __restrict__ cwT, int C) {
    __shared__ float tile[64][17];
    const int c0 = blockIdx.x * 64;
    const int j0 = blockIdx.y * 16;
    const int l  = threadIdx.x;
    #pragma unroll
    for (int it = 0; it < 4; ++it) {        // load: j-fast => coalesced reads
        int idx = it * 256 + l;
        int jj = idx & 15, cc = idx >> 4;
        int j = j0 + jj, c = c0 + cc;
        tile[cc][jj] = (j < NOUT) ? cw[(size_t)c * NOUT + j] : 0.0f;
    }
    __syncthreads();
    #pragma unroll
    for (int it = 0; it < 4; ++it) {        // store: c-fast => coalesced writes
        int idx = it * 256 + l;
        int cc = idx & 63, jj = idx >> 6;
        cwT[(size_t)(j0 + jj) * C + c0 + cc] = f2bf(tile[cc][jj]);
    }
}

// ---------- main fused layer kernel ----------
template<int FI>
__global__ __launch_bounds__(NTHR)
void cin_layer_mfma(const float* __restrict__ x0,     // [B,40,32]
                    const float* __restrict__ res,    // [B,FI,32]
                    const float* __restrict__ wq,     // [FI,32]
                    const float* __restrict__ wk,     // [40,32]
                    const float* __restrict__ wv,     // [40,32]
                    const unsigned short* __restrict__ cwT, // [208, 40*FI] bf16
                    float* __restrict__ res_out,      // [B,200,32] or nullptr
                    float* __restrict__ out,          // [B,400]
                    int out_off)
{
    constexpr int NCH = FI / FC;           // 5 or 25
    constexpr int CT  = NF0 * FI;          // cwT row length (1600 / 8000)
    constexpr int XROW = FC * NF0 + 8;     // 328 bf16, padded (16B-aligned rows)
    // smem (floats): xk[1280] | xv[1280] | q[FI*32] | XT (32*328 bf16 = 5248 f)
    constexpr int SMEMF = 2560 + FI * 32 + (32 * XROW) / 2;
    __shared__ float smem[SMEMF];

    float* s_xk = smem;
    float* s_xv = smem + 1280;
    float* s_q  = smem + 2560;
    unsigned short* s_XT = (unsigned short*)(smem + 2560 + FI * 32);
    float* s_out = smem;                   // epilogue overlay [200][33] = 6600 f

    const int tid  = threadIdx.x;
    const int b    = blockIdx.x;
    const int wid  = tid >> 6;             // 0..7
    const int lane = tid & 63;
    const int wrow = lane & 15;
    const int wq4  = lane >> 4;            // 0..3

    // ---- Phase A: elementwise products into LDS ----
    for (int idx = tid; idx < NF0 * KD; idx += NTHR) {
        float v = x0[(size_t)b * NF0 * KD + idx];
        s_xk[idx] = v * wk[idx];
        s_xv[idx] = v * wv[idx];
    }
    for (int idx = tid; idx < FI * KD; idx += NTHR)
        s_q[idx] = res[(size_t)b * FI * KD + idx] * wq[idx];
    __syncthreads();

    // wave -> j-tile assignment: wave w owns nt in {w, w+8} (13 tiles total)
    const int nt0 = wid;
    const int nt1 = wid + 8;
    const int n_nt = (nt1 < 13) ? 2 : 1;

    f32x4 acc[2][2];                       // [nt_idx][mt]
    #pragma unroll
    for (int i = 0; i < 2; ++i)
        #pragma unroll
        for (int m = 0; m < 2; ++m)
            acc[i][m] = (f32x4){0.f, 0.f, 0.f, 0.f};

    for (int ch = 0; ch < NCH; ++ch) {
        const int fi0 = ch * FC;

        // ---- softmax phase: threads 0..255, one (k, fic) each ----
        if (tid < KD * FC) {
            const int k   = tid & 31;
            const int fic = tid >> 5;
            const float qv_base = 0.0f; (void)qv_base;
            float e[NF0];
            float d = 0.0f;
            const float* qp = s_q + (fi0 + fic) * KD + k;
            #pragma unroll
            for (int f0 = 0; f0 < NF0; ++f0) {
                float p = s_xk[f0 * KD + k] * qp[0];
                e[f0] = __expf(p);
                d += e[f0];
            }
            const float r = 1.0f / d;
            #pragma unroll
            for (int f0 = 0; f0 < NF0; ++f0) {
                float xval = e[f0] * r * s_xv[f0 * KD + k];
                s_XT[k * XROW + f0 * FC + fic] = f2bf(xval);
            }
        }
        __syncthreads();

        // ---- MFMA phase: 10 K-steps of 32 over this chunk's 320 c ----
        #pragma unroll
        for (int ks = 0; ks < 10; ++ks) {
            bf16x8 a0 = *reinterpret_cast<const bf16x8*>(
                s_XT + (0 * 16 + wrow) * XROW + ks * 32 + wq4 * 8);
            bf16x8 a1 = *reinterpret_cast<const bf16x8*>(
                s_XT + (1 * 16 + wrow) * XROW + ks * 32 + wq4 * 8);
            const int f0g = ks * 4 + wq4;
            {
                const bf16x8 bfr = *reinterpret_cast<const bf16x8*>(
                    cwT + (size_t)(nt0 * 16 + wrow) * CT + f0g * FI + fi0);
                acc[0][0] = __builtin_amdgcn_mfma_f32_16x16x32_bf16(a0, bfr, acc[0][0], 0, 0, 0);
                acc[0][1] = __builtin_amdgcn_mfma_f32_16x16x32_bf16(a1, bfr, acc[0][1], 0, 0, 0);
            }
            if (n_nt == 2) {
                const bf16x8 bfr = *reinterpret_cast<const bf16x8*>(
                    cwT + (size_t)(nt1 * 16 + wrow) * CT + f0g * FI + fi0);
                acc[1][0] = __builtin_amdgcn_mfma_f32_16x16x32_bf16(a0, bfr, acc[1][0], 0, 0, 0);
                acc[1][1] = __builtin_amdgcn_mfma_f32_16x16x32_bf16(a1, bfr, acc[1][1], 0, 0, 0);
            }
        }
        __syncthreads();   // s_XT reused next chunk
    }

    // ---- Epilogue: D fragments -> s_out[j][33] ----
    // (last GEMM barrier above guarantees all s_XT reads done before overlay)
    #pragma unroll
    for (int t = 0; t < 2; ++t) {
        if (t >= n_nt) break;
        const int nt = (t == 0) ? nt0 : nt1;
        const int j  = nt * 16 + wrow;
        if (j < NOUT) {
            #pragma unroll
            for (int mt = 0; mt < 2; ++mt)
                #pragma unroll
                for (int r = 0; r < 4; ++r)
                    s_out[j * 33 + mt * 16 + wq4 * 4 + r] = acc[t][mt][r];
        }
    }
    __syncthreads();

    if (res_out != nullptr) {
        for (int idx = tid; idx < NOUT * KD; idx += NTHR)
            res_out[(size_t)b * NOUT * KD + idx] = s_out[(idx >> 5) * 33 + (idx & 31)];
    }

    if (tid < NOUT) {
        float s = 0.0f;
        #pragma unroll
        for (int k = 0; k < KD; ++k) s += s_out[tid * 33 + k];
        out[(size_t)b * 400 + out_off + tid] = s;
    }
}

extern "C" void kernel_launch(void* const* d_in, const int* in_sizes, int n_in,
                              void* d_out, int out_size, void* d_ws, size_t ws_size,
                              hipStream_t stream) {
    const float* x0  = (const float*)d_in[0];
    const float* wq0 = (const float*)d_in[1];
    const float* wk0 = (const float*)d_in[2];
    const float* wv0 = (const float*)d_in[3];
    const float* cw0 = (const float*)d_in[4];
    const float* wq1 = (const float*)d_in[5];
    const float* wk1 = (const float*)d_in[6];
    const float* wv1 = (const float*)d_in[7];
    const float* cw1 = (const float*)d_in[8];
    float* out = (float*)d_out;

    // workspace layout
    char* ws = (char*)d_ws;
    float*          res  = (float*)ws;                           // 256*200*32*4 = 6,553,600 B
    unsigned short* cwT0 = (unsigned short*)(ws + 6553600);      // 208*1600*2  =   665,600 B
    unsigned short* cwT1 = (unsigned short*)(ws + 6553600 + 665600); // 208*8000*2 = 3,328,000 B

    cw_to_bf16T<<<dim3(1600 / 64, NTP / 16), 256, 0, stream>>>(cw0, cwT0, 1600);
    cw_to_bf16T<<<dim3(8000 / 64, NTP / 16), 256, 0, stream>>>(cw1, cwT1, 8000);

    cin_layer_mfma<40><<<NB, NTHR, 0, stream>>>(x0, x0, wq0, wk0, wv0, cwT0,
                                                res, out, 0);
    cin_layer_mfma<200><<<NB, NTHR, 0, stream>>>(x0, res, wq1, wk1, wv1, cwT1,
                                                 nullptr, out, 200);
}

// Round 3
// 223.292 us; speedup vs baseline: 10.3555x; 1.7335x over previous
//
#include <hip/hip_runtime.h>
#include <hip/hip_bf16.h>

// CIN round 3: frag-packed B, fi-major c-permute, multi-batch blocks,
// XOR-swizzled LDS A-tile, full-thread softmax, bf16 res.
//
// GEMM per layer: out[b,j,k] = sum_c' X[b,k,c'] * Bp[c',j],  c' = fi*40+f0
// MFMA 16x16x32 bf16 fragment maps (verified m89/m91):
//   A[l&15][8*(l>>4)+i], B[8*(l>>4)+i][l&15], D[(l>>4)*4+r][l&15]

#define NF0   40
#define KD    32
#define NJ    200
#define NTILE 14          // N padded to 224
#define NTHR  512

typedef short bf16x8 __attribute__((ext_vector_type(8)));
typedef float f32x4  __attribute__((ext_vector_type(4)));
typedef unsigned short u16;
typedef unsigned int   u32;

static __device__ __forceinline__ u16 f2bf(float f) {
    __hip_bfloat16 h = __float2bfloat16(f);
    return *reinterpret_cast<u16*>(&h);
}
static __device__ __forceinline__ float bf2f(u16 u) {
    u32 x = ((u32)u) << 16;
    float f;
    __builtin_memcpy(&f, &x, 4);
    return f;
}

// ---- pre-pass: cw [F0*FI, 200] fp32 -> Bpack bf16, MFMA-frag-major ----
// Bpack[((nt*G + g)*64 + lane)*8 + i] = B[c' = g*32+(lane>>4)*8+i][j = nt*16+(lane&15)]
// with B[c'][j] = cw[(f0*FI+fi)*200 + j], c' = fi*40+f0 (zero-padded j>=200, fi>=FI)
template<int FI, int FIP>
__global__ __launch_bounds__(256)
void pack_b(const float* __restrict__ cw, u16* __restrict__ bp) {
    constexpr int G = FIP * NF0 / 32;
    int t = blockIdx.x * 256 + threadIdx.x;
    if (t >= NTILE * G * 64) return;
    const int lane = t & 63;
    const int g    = (t >> 6) % G;
    const int nt   = t / (64 * G);
    const int j    = nt * 16 + (lane & 15);
    const int cb   = g * 32 + (lane >> 4) * 8;
    u16 v[8];
    #pragma unroll
    for (int i = 0; i < 8; ++i) {
        int cp = cb + i;
        int fi = cp / NF0;
        int f0 = cp - fi * NF0;
        float x = (j < NJ && fi < FI) ? cw[(size_t)(f0 * FI + fi) * NJ + j] : 0.0f;
        v[i] = f2bf(x);
    }
    *reinterpret_cast<bf16x8*>(bp + (size_t)t * 8) = *reinterpret_cast<const bf16x8*>(v);
}

// ---- main fused layer kernel ----
// grid = (256/NBATCH)*NSPLIT blocks; block handles NBATCH batches, fi range
// [split*FIR, (split+1)*FIR). 8 waves = 4 M-groups x 2 N-groups; wave owns
// MT m-tiles x 7 n-tiles. Chunk = 4 fi = 160 c' = 5 K-steps.
template<int FI, int NBATCH, int NSPLIT, int FIR, int MT, bool RESBF16>
__global__ __launch_bounds__(NTHR)
void cin_layer(const float* __restrict__ x0,
               const float* __restrict__ resf,   // layer0: == x0
               const u16*  __restrict__ resb,    // layer1: bf16 res
               const float* __restrict__ wq,
               const float* __restrict__ wk,
               const float* __restrict__ wv,
               const u16* __restrict__ bp,
               u16* __restrict__ res_out,        // layer0 only
               float* __restrict__ out)          // layer1 only
{
    constexpr int M     = NBATCH * 32;
    constexpr int NCH   = FIR / 4;
    constexpr int G     = NSPLIT * FIR * NF0 / 32;  // K-steps in Bpack
    constexpr int XROWB = 384;                      // bytes per s_XT row (3x128)

    __shared__ float s_stage[NBATCH * 2560 + NBATCH * FIR * 32]; // xk|xv|q
    __shared__ u16   s_XT[M * 192];

    float* s_xk = s_stage;
    float* s_xv = s_stage + NBATCH * 1280;
    float* s_q  = s_stage + NBATCH * 2560;

    const int tid   = threadIdx.x;
    const int b0    = (blockIdx.x / NSPLIT) * NBATCH;
    const int split = blockIdx.x % NSPLIT;
    const int wid   = tid >> 6, lane = tid & 63;
    const int wrow  = lane & 15, wq4 = lane >> 4;
    const int mg    = wid & 3,  ng  = wid >> 2;

    // layer1 split0 extra duty: out[b,0:200] = sum_k res[b,j,k]
    if constexpr (NSPLIT > 1) {
        if (split == 0) {
            for (int idx = tid; idx < NBATCH * NJ; idx += NTHR) {
                int bb = idx / NJ, j = idx - bb * NJ;
                const u16* rp = resb + (size_t)(b0 + bb) * (NJ * KD) + j * KD;
                float s = 0.f;
                #pragma unroll
                for (int q8 = 0; q8 < 4; ++q8) {
                    bf16x8 v = *reinterpret_cast<const bf16x8*>(rp + q8 * 8);
                    #pragma unroll
                    for (int i = 0; i < 8; ++i) s += bf2f((u16)v[i]);
                }
                out[(size_t)(b0 + bb) * 400 + j] = s;
            }
        }
    }

    // ---- staging ----
    for (int idx = tid; idx < NBATCH * 1280; idx += NTHR) {
        int bb = idx / 1280, r = idx - bb * 1280;
        float v = x0[(size_t)(b0 + bb) * 1280 + r];
        s_xk[idx] = v * wk[r];
        s_xv[idx] = v * wv[r];
    }
    for (int idx = tid; idx < NBATCH * FIR * 32; idx += NTHR) {
        int bb = idx / (FIR * 32);
        int rr = idx - bb * (FIR * 32);
        int fi = split * FIR + (rr >> 5);
        int k  = rr & 31;
        float qv = 0.f;
        if (fi < FI) {
            float rv;
            if constexpr (RESBF16)
                rv = bf2f(resb[(size_t)(b0 + bb) * (FI * KD) + fi * KD + k]);
            else
                rv = resf[(size_t)(b0 + bb) * (FI * KD) + fi * KD + k];
            qv = rv * wq[fi * KD + k];
        }
        s_q[idx] = qv;
    }
    __syncthreads();

    f32x4 acc[MT][7];
    #pragma unroll
    for (int mt = 0; mt < MT; ++mt)
        #pragma unroll
        for (int t = 0; t < 7; ++t)
            acc[mt][t] = (f32x4){0.f, 0.f, 0.f, 0.f};

    const int gbase = split * (FIR * NF0 / 32);

    for (int ch = 0; ch < NCH; ++ch) {
        // ---- softmax: one thread per (batch, fi_local, k) ----
        if (tid < NBATCH * 128) {
            const int bb  = tid >> 7;
            const int fil = (tid >> 5) & 3;
            const int k   = tid & 31;
            const int fig = split * FIR + ch * 4 + fil;
            const int row = bb * 32 + k;
            char* rbase = (char*)s_XT + row * XROWB;
            const int swx = (row & 7) << 4;
            if (fig < FI) {
                const float qv = s_q[(bb * FIR + ch * 4 + fil) * 32 + k];
                const float* xkp = s_xk + bb * 1280 + k;
                const float* xvp = s_xv + bb * 1280 + k;
                float e[NF0];
                float d = 0.f;
                #pragma unroll
                for (int f0 = 0; f0 < NF0; ++f0) {
                    e[f0] = __expf(xkp[f0 * 32] * qv);
                    d += e[f0];
                }
                const float r = 1.0f / d;
                #pragma unroll
                for (int p = 0; p < 20; ++p) {
                    u32 w = (u32)f2bf(e[2*p]   * r * xvp[(2*p)   * 32])
                          | ((u32)f2bf(e[2*p+1] * r * xvp[(2*p+1) * 32]) << 16);
                    *reinterpret_cast<u32*>(rbase + ((fil * 80 + p * 4) ^ swx)) = w;
                }
            } else {
                #pragma unroll
                for (int p = 0; p < 20; ++p)
                    *reinterpret_cast<u32*>(rbase + ((fil * 80 + p * 4) ^ swx)) = 0u;
            }
        }
        __syncthreads();

        // ---- MFMA: 5 K-steps of 32 over the 160-c' chunk ----
        #pragma unroll
        for (int ks = 0; ks < 5; ++ks) {
            bf16x8 a[MT];
            #pragma unroll
            for (int mt = 0; mt < MT; ++mt) {
                const int row = (mg * MT + mt) * 16 + wrow;
                a[mt] = *reinterpret_cast<const bf16x8*>(
                    (char*)s_XT + row * XROWB + ((ks * 64 + wq4 * 16) ^ ((row & 7) << 4)));
            }
            const int gg = gbase + ch * 5 + ks;
            #pragma unroll
            for (int t = 0; t < 7; ++t) {
                const int nt = ng * 7 + t;
                bf16x8 bb = *reinterpret_cast<const bf16x8*>(
                    bp + ((size_t)(nt * G + gg) * 64 + lane) * 8);
                #pragma unroll
                for (int mt = 0; mt < MT; ++mt)
                    acc[mt][t] = __builtin_amdgcn_mfma_f32_16x16x32_bf16(a[mt], bb, acc[mt][t], 0, 0, 0);
            }
        }
        __syncthreads();
    }

    // ---- epilogue ----
    if constexpr (NSPLIT == 1) {
        // layer 0 (MT=1): write res bf16.  D row = mg*16 + wq4*4 + r -> (b,k)
        const int mrow = mg * 16 + wq4 * 4;
        const int bb = mrow >> 5;
        const int kk = mrow & 31;
        #pragma unroll
        for (int t = 0; t < 7; ++t) {
            const int j = (ng * 7 + t) * 16 + wrow;
            if (j < NJ) {
                u16 pk[4];
                #pragma unroll
                for (int r = 0; r < 4; ++r) pk[r] = f2bf(acc[0][t][r]);
                *reinterpret_cast<unsigned long long*>(
                    res_out + (size_t)(b0 + bb) * (NJ * KD) + j * KD + kk)
                    = *reinterpret_cast<const unsigned long long*>(pk);
            }
        }
    } else {
        // layer 1 (MT=2): batch == mg; k-sum via shuffle, then atomicAdd partials
        #pragma unroll
        for (int t = 0; t < 7; ++t) {
            float s = 0.f;
            #pragma unroll
            for (int mt = 0; mt < MT; ++mt)
                #pragma unroll
                for (int r = 0; r < 4; ++r) s += acc[mt][t][r];
            s += __shfl_xor(s, 16);
            s += __shfl_xor(s, 32);
            const int j = (ng * 7 + t) * 16 + wrow;
            if (wq4 == 0 && j < NJ)
                atomicAdd(&out[(size_t)(b0 + mg) * 400 + 200 + j], s);
        }
    }
}

extern "C" void kernel_launch(void* const* d_in, const int* in_sizes, int n_in,
                              void* d_out, int out_size, void* d_ws, size_t ws_size,
                              hipStream_t stream) {
    const float* x0  = (const float*)d_in[0];
    const float* wq0 = (const float*)d_in[1];
    const float* wk0 = (const float*)d_in[2];
    const float* wv0 = (const float*)d_in[3];
    const float* cw0 = (const float*)d_in[4];
    const float* wq1 = (const float*)d_in[5];
    const float* wk1 = (const float*)d_in[6];
    const float* wv1 = (const float*)d_in[7];
    const float* cw1 = (const float*)d_in[8];
    float* out = (float*)d_out;

    // ws: res bf16 [256*200*32] | Bpack0 | Bpack1
    char* ws = (char*)d_ws;
    u16* res = (u16*)ws;                              // 3,276,800 B
    u16* bp0 = (u16*)(ws + 3276800);                  //   716,800 B (14*50*512)
    u16* bp1 = (u16*)(ws + 3276800 + 716800);         // 3,727,360 B (14*260*512)

    hipMemsetAsync(d_out, 0, (size_t)out_size * 4, stream);

    pack_b<40, 40>  <<<175, 256, 0, stream>>>(cw0, bp0);   // G=50
    pack_b<200, 208><<<910, 256, 0, stream>>>(cw1, bp1);   // G=260

    // layer 0: 128 blocks x 2 batches, no split, full C (10 chunks)
    cin_layer<40, 2, 1, 40, 1, false><<<128, NTHR, 0, stream>>>(
        x0, x0, nullptr, wq0, wk0, wv0, bp0, res, nullptr);

    // layer 1: 64 bg x 4 fi-splits (52 fi, 13 chunks), atomic k-sum finish
    cin_layer<200, 4, 4, 52, 2, true><<<256, NTHR, 0, stream>>>(
        x0, nullptr, res, wq1, wk1, wv1, bp1, nullptr, out);
}

// Round 4
// 199.793 us; speedup vs baseline: 11.5735x; 1.1176x over previous
//
#include <hip/hip_runtime.h>
#include <hip/hip_bf16.h>

// CIN round 4: occupancy + phase overlap.
//  - layer1: NBATCH=2, 58KB LDS, 2 blocks/CU, all-thread h-split softmax
//  - layer0: 512 blocks (256 b x 2 j-splits), chunk=8fi, all-thread softmax
//  - coalesced pack_b (LDS transpose), setprio around MFMA
// GEMM: out[b,j,k] = sum_c' X[b,k,c'] * Bp[c',j], c' = fi*40+f0 (fi-major)
// MFMA 16x16x32 bf16 frag maps (m89/m91):
//   A[l&15][8*(l>>4)+i], B[8*(l>>4)+i][l&15], D[(l>>4)*4+r][l&15]

#define NF0   40
#define KD    32
#define NJ    200
#define NTILE 14
#define NTHR  512

typedef short bf16x8 __attribute__((ext_vector_type(8)));
typedef float f32x4  __attribute__((ext_vector_type(4)));
typedef unsigned short u16;
typedef unsigned int   u32;
typedef unsigned long long u64;

static __device__ __forceinline__ u16 f2bf(float f) {
    __hip_bfloat16 h = __float2bfloat16(f);
    return *reinterpret_cast<u16*>(&h);
}
static __device__ __forceinline__ float bf2f(u16 u) {
    u32 x = ((u32)u) << 16;
    float f;
    __builtin_memcpy(&f, &x, 4);
    return f;
}

// ---- pack: cw [f0*FI+fi, 200] fp32 -> Bpack bf16 frag-major, c' = fi*40+f0 ----
// Bpack[((nt*G + g)*64 + lane)*8 + i] = B[c' = g*32+(lane>>4)*8+i][j = nt*16+(lane&15)]
// grid (G/2 bands of 64 c', NTILE), 256 thr. Coalesced float4 row loads.
template<int FI>
__global__ __launch_bounds__(256)
void pack_b(const float* __restrict__ cw, u16* __restrict__ bp, int G) {
    __shared__ float tile[64][17];
    const int band = blockIdx.x, nt = blockIdx.y;
    const int t = threadIdx.x;
    {
        const int cl = t >> 2, qj = t & 3;
        const int cp = band * 64 + cl;
        const int fi = cp / NF0, f0 = cp - fi * NF0;
        const int j0 = nt * 16 + qj * 4;
        float4 v = make_float4(0.f, 0.f, 0.f, 0.f);
        if (fi < FI) {
            const float* src = cw + (size_t)(f0 * FI + fi) * NJ + j0;
            if (j0 + 3 < NJ) v = *reinterpret_cast<const float4*>(src);
            else {
                if (j0 + 0 < NJ) v.x = src[0];
                if (j0 + 1 < NJ) v.y = src[1];
                if (j0 + 2 < NJ) v.z = src[2];
                if (j0 + 3 < NJ) v.w = src[3];
            }
        }
        tile[cl][qj * 4 + 0] = v.x;
        tile[cl][qj * 4 + 1] = v.y;
        tile[cl][qj * 4 + 2] = v.z;
        tile[cl][qj * 4 + 3] = v.w;
    }
    __syncthreads();
    if (t < 128) {
        const int g2 = t >> 6, lane = t & 63;
        const int jl = lane & 15, c8 = g2 * 32 + (lane >> 4) * 8;
        u16 v[8];
        #pragma unroll
        for (int i = 0; i < 8; ++i) v[i] = f2bf(tile[c8 + i][jl]);
        *reinterpret_cast<bf16x8*>(bp + ((size_t)(nt * G + band * 2 + g2) * 64 + lane) * 8)
            = *reinterpret_cast<const bf16x8*>(v);
    }
}

// ---- layer 0: grid 512 = (b 256) x (jsplit 2), chunk = 8 fi, res -> bf16 ----
__global__ __launch_bounds__(NTHR, 4)
void cin_layer0(const float* __restrict__ x0,
                const float* __restrict__ wq, const float* __restrict__ wk,
                const float* __restrict__ wv,
                const u16* __restrict__ bp, u16* __restrict__ res) {
    constexpr int G0 = 50;
    __shared__ float s_xk[1280], s_xv[1280], s_q[1280];
    __shared__ u16 s_XT[32 * 384];   // 32 rows x 768 B (chunk: 8fi*40f0 = 640B + pad)

    const int tid = threadIdx.x;
    const int b = blockIdx.x >> 1, js = blockIdx.x & 1;
    const int wid = tid >> 6, lane = tid & 63;
    const int wrow = lane & 15, wq4 = lane >> 4;
    const int mg = wid & 1, ng = wid >> 1;

    for (int i = tid; i < 1280; i += NTHR) {
        float v = x0[(size_t)b * 1280 + i];
        s_xk[i] = v * wk[i];
        s_xv[i] = v * wv[i];
        s_q[i]  = v * wq[i];
    }
    __syncthreads();

    f32x4 acc[2];
    #pragma unroll
    for (int t = 0; t < 2; ++t) acc[t] = (f32x4){0.f, 0.f, 0.f, 0.f};

    const int sfil = tid >> 6, sh = (tid >> 5) & 1, sk = tid & 31;
    char* srb = (char*)s_XT + sk * 768;
    const int sswx = (sk & 7) << 4;
    const int arow = mg * 16 + wrow;
    char* apb = (char*)s_XT + arow * 768;
    const int aswx = (arow & 7) << 4;

    for (int ch = 0; ch < 5; ++ch) {
        // softmax: all 512 threads, (fil 8, h 2, k 32); h halves f0
        {
            const float qv = s_q[(ch * 8 + sfil) * 32 + sk];
            const float* xkp = s_xk + sh * 640 + sk;
            const float* xvp = s_xv + sh * 640 + sk;
            float e[20];
            float d = 0.f;
            #pragma unroll
            for (int i = 0; i < 20; ++i) {
                e[i] = __expf(xkp[i * 32] * qv);
                d += e[i];
            }
            d += __shfl_xor(d, 32);
            const float r = 1.0f / d;
            #pragma unroll
            for (int p = 0; p < 10; ++p) {
                u32 w = (u32)f2bf(e[2 * p] * r * xvp[(2 * p) * 32])
                      | ((u32)f2bf(e[2 * p + 1] * r * xvp[(2 * p + 1) * 32]) << 16);
                *reinterpret_cast<u32*>(srb + ((sfil * 80 + sh * 40 + p * 4) ^ sswx)) = w;
            }
        }
        __syncthreads();
        __builtin_amdgcn_s_setprio(1);
        #pragma unroll
        for (int ks = 0; ks < 10; ++ks) {
            bf16x8 a = *reinterpret_cast<const bf16x8*>(apb + ((ks * 64 + wq4 * 16) ^ aswx));
            const int g = ch * 10 + ks;
            #pragma unroll
            for (int t = 0; t < 2; ++t) {
                const int ntl = ng * 2 + t;
                if (ntl < 7) {
                    const int nt = js * 7 + ntl;
                    bf16x8 bfr = *reinterpret_cast<const bf16x8*>(
                        bp + ((size_t)(nt * G0 + g) * 64 + lane) * 8);
                    acc[t] = __builtin_amdgcn_mfma_f32_16x16x32_bf16(a, bfr, acc[t], 0, 0, 0);
                }
            }
        }
        __builtin_amdgcn_s_setprio(0);
        __syncthreads();
    }

    // epilogue: res[b][j][k] bf16; D row (= k) = mg*16 + wq4*4 + r
    const int kbase = mg * 16 + wq4 * 4;
    #pragma unroll
    for (int t = 0; t < 2; ++t) {
        const int ntl = ng * 2 + t;
        if (ntl < 7) {
            const int j = (js * 7 + ntl) * 16 + wrow;
            if (j < NJ) {
                u16 pk[4];
                #pragma unroll
                for (int r = 0; r < 4; ++r) pk[r] = f2bf(acc[t][r]);
                *reinterpret_cast<u64*>(res + (size_t)b * (NJ * KD) + j * KD + kbase)
                    = *reinterpret_cast<const u64*>(pk);
            }
        }
    }
}

// ---- layer 1: grid 512 = (bg 128, NBATCH=2) x (fi-split 4), chunk = 4 fi ----
__global__ __launch_bounds__(NTHR, 4)
void cin_layer1(const float* __restrict__ x0, const u16* __restrict__ resb,
                const float* __restrict__ wq, const float* __restrict__ wk,
                const float* __restrict__ wv,
                const u16* __restrict__ bp, float* __restrict__ out) {
    constexpr int G1 = 260, FIR = 52;
    __shared__ float s_xk[2560], s_xv[2560], s_q[2 * FIR * 32];  // 33.8 KB
    __shared__ u16 s_XT[64 * 192];                               // 64 rows x 384 B

    const int tid = threadIdx.x;
    const int bg = blockIdx.x >> 2, split = blockIdx.x & 3;
    const int b0 = bg * 2;
    const int wid = tid >> 6, lane = tid & 63;
    const int wrow = lane & 15, wq4 = lane >> 4;
    const int mg = wid & 3, ng = wid >> 2;

    // split-0 duty: out[b, 0:200] = sum_k res[b,j,k]
    if (split == 0) {
        for (int idx = tid; idx < 2 * NJ; idx += NTHR) {
            const int bb = idx / NJ, j = idx - bb * NJ;
            const u16* rp = resb + (size_t)(b0 + bb) * (NJ * KD) + j * KD;
            float s = 0.f;
            #pragma unroll
            for (int q8 = 0; q8 < 4; ++q8) {
                bf16x8 v = *reinterpret_cast<const bf16x8*>(rp + q8 * 8);
                #pragma unroll
                for (int i = 0; i < 8; ++i) s += bf2f((u16)v[i]);
            }
            out[(size_t)(b0 + bb) * 400 + j] = s;
        }
    }

    for (int idx = tid; idx < 2560; idx += NTHR) {
        const int bb = idx / 1280, r = idx - bb * 1280;
        float v = x0[(size_t)(b0 + bb) * 1280 + r];
        s_xk[idx] = v * wk[r];
        s_xv[idx] = v * wv[r];
    }
    for (int idx = tid; idx < 2 * FIR * 32; idx += NTHR) {
        const int bb = idx / (FIR * 32), rr = idx - bb * (FIR * 32);
        const int fi = split * FIR + (rr >> 5), k = rr & 31;
        float qv = 0.f;
        if (fi < 200)
            qv = bf2f(resb[(size_t)(b0 + bb) * (NJ * KD) + fi * KD + k]) * wq[fi * KD + k];
        s_q[idx] = qv;
    }
    __syncthreads();

    f32x4 acc[7];
    #pragma unroll
    for (int t = 0; t < 7; ++t) acc[t] = (f32x4){0.f, 0.f, 0.f, 0.f};

    const int sbb = tid >> 8, sfil = (tid >> 6) & 3, sh = (tid >> 5) & 1, sk = tid & 31;
    const int srow = sbb * 32 + sk;
    char* srb = (char*)s_XT + srow * 384;
    const int sswx = (srow & 7) << 4;
    const int arow = mg * 16 + wrow;
    char* apb = (char*)s_XT + arow * 384;
    const int aswx = (arow & 7) << 4;

    for (int ch = 0; ch < 13; ++ch) {
        const int fig = split * FIR + ch * 4 + sfil;
        if (fig < 200) {
            const float qv = s_q[sbb * (FIR * 32) + (ch * 4 + sfil) * 32 + sk];
            const float* xkp = s_xk + sbb * 1280 + sh * 640 + sk;
            const float* xvp = s_xv + sbb * 1280 + sh * 640 + sk;
            float e[20];
            float d = 0.f;
            #pragma unroll
            for (int i = 0; i < 20; ++i) {
                e[i] = __expf(xkp[i * 32] * qv);
                d += e[i];
            }
            d += __shfl_xor(d, 32);
            const float r = 1.0f / d;
            #pragma unroll
            for (int p = 0; p < 10; ++p) {
                u32 w = (u32)f2bf(e[2 * p] * r * xvp[(2 * p) * 32])
                      | ((u32)f2bf(e[2 * p + 1] * r * xvp[(2 * p + 1) * 32]) << 16);
                *reinterpret_cast<u32*>(srb + ((sfil * 80 + sh * 40 + p * 4) ^ sswx)) = w;
            }
        } else {
            #pragma unroll
            for (int p = 0; p < 10; ++p)
                *reinterpret_cast<u32*>(srb + ((sfil * 80 + sh * 40 + p * 4) ^ sswx)) = 0u;
        }
        __syncthreads();
        __builtin_amdgcn_s_setprio(1);
        #pragma unroll
        for (int ks = 0; ks < 5; ++ks) {
            bf16x8 a = *reinterpret_cast<const bf16x8*>(apb + ((ks * 64 + wq4 * 16) ^ aswx));
            const int g = split * 65 + ch * 5 + ks;
            #pragma unroll
            for (int t = 0; t < 7; ++t) {
                const int nt2 = ng * 7 + t;
                bf16x8 bfr = *reinterpret_cast<const bf16x8*>(
                    bp + ((size_t)(nt2 * G1 + g) * 64 + lane) * 8);
                acc[t] = __builtin_amdgcn_mfma_f32_16x16x32_bf16(a, bfr, acc[t], 0, 0, 0);
            }
        }
        __builtin_amdgcn_s_setprio(0);
        __syncthreads();
    }

    // epilogue: wave owns m-tile mg -> batch bb=mg>>1, 16 k-rows; k-sum + atomic
    #pragma unroll
    for (int t = 0; t < 7; ++t) {
        float s = acc[t][0] + acc[t][1] + acc[t][2] + acc[t][3];
        s += __shfl_xor(s, 16);
        s += __shfl_xor(s, 32);
        const int j = (ng * 7 + t) * 16 + wrow;
        if (wq4 == 0 && j < NJ) {
            const int bb = mg >> 1;
            atomicAdd(&out[(size_t)(b0 + bb) * 400 + 200 + j], s);
        }
    }
}

extern "C" void kernel_launch(void* const* d_in, const int* in_sizes, int n_in,
                              void* d_out, int out_size, void* d_ws, size_t ws_size,
                              hipStream_t stream) {
    const float* x0  = (const float*)d_in[0];
    const float* wq0 = (const float*)d_in[1];
    const float* wk0 = (const float*)d_in[2];
    const float* wv0 = (const float*)d_in[3];
    const float* cw0 = (const float*)d_in[4];
    const float* wq1 = (const float*)d_in[5];
    const float* wk1 = (const float*)d_in[6];
    const float* wv1 = (const float*)d_in[7];
    const float* cw1 = (const float*)d_in[8];
    float* out = (float*)d_out;

    char* ws = (char*)d_ws;
    u16* res = (u16*)ws;                          // 256*200*32*2 = 3,276,800 B
    u16* bp0 = (u16*)(ws + 3276800);              // 14*50*512*2  =   716,800 B
    u16* bp1 = (u16*)(ws + 3276800 + 716800);     // 14*260*512*2 = 3,727,360 B

    hipMemsetAsync(d_out, 0, (size_t)out_size * 4, stream);

    pack_b<40> <<<dim3(25, NTILE), 256, 0, stream>>>(cw0, bp0, 50);
    pack_b<200><<<dim3(130, NTILE), 256, 0, stream>>>(cw1, bp1, 260);

    cin_layer0<<<512, NTHR, 0, stream>>>(x0, wq0, wk0, wv0, bp0, res);
    cin_layer1<<<512, NTHR, 0, stream>>>(x0, res, wq1, wk1, wv1, bp1, out);
}

// Round 5
// 187.554 us; speedup vs baseline: 12.3288x; 1.0653x over previous
//
#include <hip/hip_runtime.h>
#include <hip/hip_bf16.h>

// CIN round 5: 32x32x16 MFMA (2x flop/byte and flop/instr vs 16x16x32),
// register-hoisted softmax operands, b64 LDS stores, no-atomic layer0 via
// two res halves, read-once pack.
//
// GEMM per layer: out[b,j,k] = sum_c' X[b,k,c'] * Bp[c',j],  c' = fi*40+f0
// mfma_f32_32x32x16_bf16 frag maps: A[l&31][8*(l>>5)+i], B[8*(l>>5)+i][l&31],
// C/D: col=l&31, row=(reg&3)+8*(reg>>2)+4*(l>>5)   [C/D HW-verified m74/m101]

#define NF0  40
#define KD   32
#define NJ   200
#define NTHR 512

typedef short bf16x8 __attribute__((ext_vector_type(8)));
typedef float f32x16 __attribute__((ext_vector_type(16)));
typedef unsigned short u16;
typedef unsigned int   u32;
typedef unsigned long long u64;

static __device__ __forceinline__ u16 f2bf(float f) {
    __hip_bfloat16 h = __float2bfloat16(f);
    return *reinterpret_cast<u16*>(&h);
}
static __device__ __forceinline__ float bf2f(u16 u) {
    u32 x = ((u32)u) << 16;
    float f;
    __builtin_memcpy(&f, &x, 4);
    return f;
}

// ---- pack: cw [f0*FI+fi, 200] -> Bpack frag-major for 32x32x16, c'=fi*40+f0 ----
// Bpack[((nt*G + g)*64 + l)*8 + i] = B[c'=g*16+8*(l>>5)+i][j=nt*32+(l&31)]
// block = (band of 4 fi -> 10 g, nt). cw read exactly once, float4-coalesced.
template<int FI>
__global__ __launch_bounds__(256)
void pack_b(const float* __restrict__ cw, u16* __restrict__ bp, int G) {
    __shared__ u16 s[160][33];
    const int fi0 = blockIdx.x * 4;
    const int nt  = blockIdx.y;
    const int t   = threadIdx.x;
    #pragma unroll
    for (int it = 0; it < 5; ++it) {
        int idx = it * 256 + t;          // 1280 float4 slots
        int rl = idx >> 3, q4 = idx & 7;
        int f0 = rl >> 2, fl = rl & 3;
        int fi = fi0 + fl;
        int j0 = nt * 32 + q4 * 4;
        float4 v = make_float4(0.f, 0.f, 0.f, 0.f);
        if (fi < FI && j0 <= NJ - 4)
            v = *reinterpret_cast<const float4*>(cw + (size_t)(f0 * FI + fi) * NJ + j0);
        int cl = fl * 40 + f0;
        s[cl][q4 * 4 + 0] = f2bf(v.x);
        s[cl][q4 * 4 + 1] = f2bf(v.y);
        s[cl][q4 * 4 + 2] = f2bf(v.z);
        s[cl][q4 * 4 + 3] = f2bf(v.w);
    }
    __syncthreads();
    for (int ft = t; ft < 640; ft += 256) {
        int g = ft >> 6, l = ft & 63;
        u16 v[8];
        #pragma unroll
        for (int i = 0; i < 8; ++i) v[i] = s[g * 16 + 8 * (l >> 5) + i][l & 31];
        *reinterpret_cast<bf16x8*>(bp + ((size_t)(nt * G + blockIdx.x * 10 + g) * 64 + l) * 8)
            = *reinterpret_cast<const bf16x8*>(v);
    }
}

// ---- layer 0: grid 512 = 256 b x 2 fi-halves (20 fi each, 5 chunks of 4) ----
// res partials: resp[half][b][j][k] bf16 (summed at layer1 staging; no atomics)
__global__ __launch_bounds__(NTHR, 4)
void cin_layer0(const float* __restrict__ x0,
                const float* __restrict__ wq, const float* __restrict__ wk,
                const float* __restrict__ wv,
                const u16* __restrict__ bp, u16* __restrict__ resp) {
    __shared__ float s_xk[1280], s_xv[1280], s_q[640];
    __shared__ u64 s_XT[32 * 48];            // 32 rows x 384 B
    const int tid = threadIdx.x;
    const int b = blockIdx.x >> 1, half = blockIdx.x & 1;
    const int wid = tid >> 6, lane = tid & 63;
    const int jcol = lane & 31, hh = lane >> 5;

    for (int i = tid; i < 1280; i += NTHR) {
        float v = x0[(size_t)b * 1280 + i];
        s_xk[i] = v * wk[i];
        s_xv[i] = v * wv[i];
    }
    for (int i = tid; i < 640; i += NTHR) {
        int fi = half * 20 + (i >> 5), k = i & 31;
        s_q[i] = x0[(size_t)b * 1280 + fi * 32 + k] * wq[fi * 32 + k];
    }
    __syncthreads();

    // hoist chunk-invariant xk/xv slices (softmax waves 0..3 only)
    const int sk = lane & 31, sh = lane >> 5, sfil = wid;
    float xkr[20], xvr[20];
    if (wid < 4) {
        #pragma unroll
        for (int i = 0; i < 20; ++i) {
            xkr[i] = s_xk[(sh * 20 + i) * 32 + sk];
            xvr[i] = s_xv[(sh * 20 + i) * 32 + sk];
        }
    }

    f32x16 acc;
    #pragma unroll
    for (int r = 0; r < 16; ++r) acc[r] = 0.f;
    const int nt = wid;                       // waves 0..6 own one n-tile
    char* aptr = (char*)s_XT + jcol * 384;
    const int aswz = (jcol & 7) << 4;

    for (int ch = 0; ch < 5; ++ch) {
        if (wid < 4) {
            const float q = s_q[(ch * 4 + sfil) * 32 + sk];
            float e[20], d = 0.f;
            #pragma unroll
            for (int i = 0; i < 20; ++i) { e[i] = __expf(xkr[i] * q); d += e[i]; }
            d += __shfl_xor(d, 32);
            const float rr = 1.0f / d;
            char* rb = (char*)s_XT + sk * 384;
            const int swz = (sk & 7) << 4;
            #pragma unroll
            for (int p = 0; p < 5; ++p) {
                u64 w = (u64)f2bf(e[4*p+0] * rr * xvr[4*p+0])
                      | ((u64)f2bf(e[4*p+1] * rr * xvr[4*p+1]) << 16)
                      | ((u64)f2bf(e[4*p+2] * rr * xvr[4*p+2]) << 32)
                      | ((u64)f2bf(e[4*p+3] * rr * xvr[4*p+3]) << 48);
                *reinterpret_cast<u64*>(rb + ((sfil * 80 + sh * 40 + p * 8) ^ swz)) = w;
            }
        }
        __syncthreads();
        __builtin_amdgcn_s_setprio(1);
        if (wid < 7) {
            #pragma unroll
            for (int ks = 0; ks < 10; ++ks) {
                bf16x8 a = *reinterpret_cast<const bf16x8*>(aptr + ((ks * 32 + hh * 16) ^ aswz));
                const int g = half * 50 + ch * 10 + ks;
                bf16x8 bf = *reinterpret_cast<const bf16x8*>(
                    bp + ((size_t)(nt * 100 + g) * 64 + lane) * 8);
                acc = __builtin_amdgcn_mfma_f32_32x32x16_bf16(a, bf, acc, 0, 0, 0);
            }
        }
        __builtin_amdgcn_s_setprio(0);
        __syncthreads();
    }

    if (wid < 7) {
        const int j = nt * 32 + jcol;
        if (j < NJ) {
            u16* dst = resp + (size_t)(half * 256 + b) * 6400 + j * 32;
            #pragma unroll
            for (int rg = 0; rg < 4; ++rg) {     // rows k = 8*rg + 4*hh + 0..3
                u64 w = (u64)f2bf(acc[4*rg+0]) | ((u64)f2bf(acc[4*rg+1]) << 16)
                      | ((u64)f2bf(acc[4*rg+2]) << 32) | ((u64)f2bf(acc[4*rg+3]) << 48);
                *reinterpret_cast<u64*>(dst + 8 * rg + 4 * hh) = w;
            }
        }
    }
}

// ---- layer 1: grid 512 = 128 bg(2 batches) x 4 fi-splits (52 fi, 13 chunks) ----
__global__ __launch_bounds__(NTHR, 4)
void cin_layer1(const float* __restrict__ x0, const u16* __restrict__ resp,
                const float* __restrict__ wq, const float* __restrict__ wk,
                const float* __restrict__ wv,
                const u16* __restrict__ bp, float* __restrict__ out) {
    __shared__ float s_xk[2560], s_xv[2560], s_q[3328];
    __shared__ u64 s_XT[64 * 48];            // 64 rows x 384 B
    const int tid = threadIdx.x;
    const int bg = blockIdx.x >> 2, split = blockIdx.x & 3;
    const int b0 = bg * 2;
    const int wid = tid >> 6, lane = tid & 63;

    // split-0 duty: out[b, 0:200] = sum_k (resp0 + resp1)
    if (split == 0) {
        for (int idx = tid; idx < 2 * NJ; idx += NTHR) {
            const int bb = idx / NJ, j = idx - bb * NJ;
            const u16* r0 = resp + (size_t)(b0 + bb) * 6400 + j * 32;
            const u16* r1 = resp + (size_t)(256 + b0 + bb) * 6400 + j * 32;
            float s = 0.f;
            #pragma unroll
            for (int q8 = 0; q8 < 4; ++q8) {
                bf16x8 v0 = *reinterpret_cast<const bf16x8*>(r0 + q8 * 8);
                bf16x8 v1 = *reinterpret_cast<const bf16x8*>(r1 + q8 * 8);
                #pragma unroll
                for (int i = 0; i < 8; ++i) s += bf2f((u16)v0[i]) + bf2f((u16)v1[i]);
            }
            out[(size_t)(b0 + bb) * 400 + j] = s;
        }
    }

    for (int idx = tid; idx < 2560; idx += NTHR) {
        const int bb = idx / 1280, r = idx - bb * 1280;
        float v = x0[(size_t)(b0 + bb) * 1280 + r];
        s_xk[idx] = v * wk[r];
        s_xv[idx] = v * wv[r];
    }
    for (int idx = tid; idx < 3328; idx += NTHR) {
        const int bb = idx / 1664, rr = idx - bb * 1664;
        const int fi = split * 52 + (rr >> 5), k = rr & 31;
        float qv = 0.f;
        if (fi < 200) {
            float rv = bf2f(resp[(size_t)(b0 + bb) * 6400 + fi * 32 + k])
                     + bf2f(resp[(size_t)(256 + b0 + bb) * 6400 + fi * 32 + k]);
            qv = rv * wq[fi * 32 + k];
        }
        s_q[idx] = qv;
    }
    __syncthreads();

    const int sbb = wid >> 2, sfil = wid & 3, sh = lane >> 5, sk = lane & 31;
    const int srow = sbb * 32 + sk;
    float xkr[20], xvr[20];
    #pragma unroll
    for (int i = 0; i < 20; ++i) {
        xkr[i] = s_xk[sbb * 1280 + (sh * 20 + i) * 32 + sk];
        xvr[i] = s_xv[sbb * 1280 + (sh * 20 + i) * 32 + sk];
    }
    char* srb = (char*)s_XT + srow * 384;
    const int sswz = (srow & 7) << 4;

    const int mg = wid & 1, ng = wid >> 1;
    const int nt0 = ng, nt1 = ng + 4;
    const int ntc = (ng < 3) ? 2 : 1;
    f32x16 acc[2];
    #pragma unroll
    for (int t = 0; t < 2; ++t)
        #pragma unroll
        for (int r = 0; r < 16; ++r) acc[t][r] = 0.f;
    const int arow = mg * 32 + (lane & 31);
    char* aptr = (char*)s_XT + arow * 384;
    const int aswz = (arow & 7) << 4;
    const int ah = (lane >> 5) * 16;

    for (int ch = 0; ch < 13; ++ch) {
        const int fig = split * 52 + ch * 4 + sfil;
        if (fig < 200) {
            const float q = s_q[sbb * 1664 + (ch * 4 + sfil) * 32 + sk];
            float e[20], d = 0.f;
            #pragma unroll
            for (int i = 0; i < 20; ++i) { e[i] = __expf(xkr[i] * q); d += e[i]; }
            d += __shfl_xor(d, 32);
            const float rr = 1.0f / d;
            #pragma unroll
            for (int p = 0; p < 5; ++p) {
                u64 w = (u64)f2bf(e[4*p+0] * rr * xvr[4*p+0])
                      | ((u64)f2bf(e[4*p+1] * rr * xvr[4*p+1]) << 16)
                      | ((u64)f2bf(e[4*p+2] * rr * xvr[4*p+2]) << 32)
                      | ((u64)f2bf(e[4*p+3] * rr * xvr[4*p+3]) << 48);
                *reinterpret_cast<u64*>(srb + ((sfil * 80 + sh * 40 + p * 8) ^ sswz)) = w;
            }
        } else {
            #pragma unroll
            for (int p = 0; p < 5; ++p)
                *reinterpret_cast<u64*>(srb + ((sfil * 80 + sh * 40 + p * 8) ^ sswz)) = 0ull;
        }
        __syncthreads();
        __builtin_amdgcn_s_setprio(1);
        #pragma unroll
        for (int ks = 0; ks < 10; ++ks) {
            bf16x8 a = *reinterpret_cast<const bf16x8*>(aptr + ((ks * 32 + ah) ^ aswz));
            const int g = split * 130 + ch * 10 + ks;
            bf16x8 bf0 = *reinterpret_cast<const bf16x8*>(
                bp + ((size_t)(nt0 * 520 + g) * 64 + lane) * 8);
            acc[0] = __builtin_amdgcn_mfma_f32_32x32x16_bf16(a, bf0, acc[0], 0, 0, 0);
            if (ntc == 2) {
                bf16x8 bf1 = *reinterpret_cast<const bf16x8*>(
                    bp + ((size_t)(nt1 * 520 + g) * 64 + lane) * 8);
                acc[1] = __builtin_amdgcn_mfma_f32_32x32x16_bf16(a, bf1, acc[1], 0, 0, 0);
            }
        }
        __builtin_amdgcn_s_setprio(0);
        __syncthreads();
    }

    // epilogue: k-sum (16 regs = k-rows of this m-tile/batch, + lane^32 half)
    #pragma unroll
    for (int t = 0; t < 2; ++t) {
        if (t < ntc) {
            float s = 0.f;
            #pragma unroll
            for (int r = 0; r < 16; ++r) s += acc[t][r];
            s += __shfl_xor(s, 32);
            const int nt = (t == 0) ? nt0 : nt1;
            const int j = nt * 32 + (lane & 31);
            if (lane < 32 && j < NJ)
                atomicAdd(&out[(size_t)(b0 + mg) * 400 + 200 + j], s);
        }
    }
}

extern "C" void kernel_launch(void* const* d_in, const int* in_sizes, int n_in,
                              void* d_out, int out_size, void* d_ws, size_t ws_size,
                              hipStream_t stream) {
    const float* x0  = (const float*)d_in[0];
    const float* wq0 = (const float*)d_in[1];
    const float* wk0 = (const float*)d_in[2];
    const float* wv0 = (const float*)d_in[3];
    const float* cw0 = (const float*)d_in[4];
    const float* wq1 = (const float*)d_in[5];
    const float* wk1 = (const float*)d_in[6];
    const float* wv1 = (const float*)d_in[7];
    const float* cw1 = (const float*)d_in[8];
    float* out = (float*)d_out;

    char* ws = (char*)d_ws;
    u16* resp = (u16*)ws;                          // 2*256*6400*2 = 6,553,600 B
    u16* bp0  = (u16*)(ws + 6553600);              // 7*100*512*2  =   716,800 B
    u16* bp1  = (u16*)(ws + 6553600 + 716800);     // 7*520*512*2  = 3,727,360 B

    hipMemsetAsync(d_out, 0, (size_t)out_size * 4, stream);

    pack_b<40> <<<dim3(10, 7), 256, 0, stream>>>(cw0, bp0, 100);
    pack_b<200><<<dim3(52, 7), 256, 0, stream>>>(cw1, bp1, 520);

    cin_layer0<<<512, NTHR, 0, stream>>>(x0, wq0, wk0, wv0, bp0, resp);
    cin_layer1<<<512, NTHR, 0, stream>>>(x0, resp, wq1, wk1, wv1, bp1, out);
}